// Round 8
// baseline (178.005 us; speedup 1.0000x reference)
//
#include <hip/hip_runtime.h>
#include <math.h>

// Problem constants (from reference)
#define BATCH 16
#define NBOX  2000
#define NCLS  81
#define NCLS1 80        // classes 1..80 participate in NMS (class 0 invalid)
#define MAXI  100
#define ROWS_PB 128     // rows per block in phase 1
#define SURV_MAX 2048   // per-batch survivor list capacity (>= NBOX)
#define NBUCK 1024
#define CANDCAP 1024

// Refine with known class id — bit-exact vs numpy reference (absmax 0.0 R1-R7).
__device__ __forceinline__ void apply_refine(
    const float* __restrict__ rois, const float* __restrict__ deltas,
    size_t row, int cid, float box[4])
{
    const float4 dr = *(const float4*)(deltas + (row * NCLS + cid) * 4);
    const float4 r  = *(const float4*)(rois + row * 4);
    float dy = __fmul_rn(dr.x, 0.1f);
    float dx = __fmul_rn(dr.y, 0.1f);
    float dh = __fmul_rn(dr.z, 0.2f);
    float dw = __fmul_rn(dr.w, 0.2f);
    float h = __fsub_rn(r.z, r.x);
    float w = __fsub_rn(r.w, r.y);
    float cy = __fadd_rn(r.x, __fmul_rn(0.5f, h));
    float cx = __fadd_rn(r.y, __fmul_rn(0.5f, w));
    cy = __fadd_rn(cy, __fmul_rn(dy, h));
    cx = __fadd_rn(cx, __fmul_rn(dx, w));
    h = __fmul_rn(h, (float)exp((double)dh));   // correctly-rounded f32 exp
    w = __fmul_rn(w, (float)exp((double)dw));
    float hy = __fmul_rn(0.5f, h), hx = __fmul_rn(0.5f, w);
    box[0] = fminf(fmaxf(__fsub_rn(cy, hy), 0.f), 1.f);
    box[1] = fminf(fmaxf(__fsub_rn(cx, hx), 0.f), 1.f);
    box[2] = fminf(fmaxf(__fadd_rn(cy, hy), 0.f), 1.f);
    box[3] = fminf(fmaxf(__fadd_rn(cx, hx), 0.f), 1.f);
}

__device__ __forceinline__ unsigned long long shfl_u64(unsigned long long v, int src) {
    unsigned lo = __shfl((unsigned)v, src);
    unsigned hi = __shfl((unsigned)(v >> 32), src);
    return ((unsigned long long)hi << 32) | lo;
}

// Monotonic score-bucket: keys ascend == scores descend; valid scores in [0.7,1)
// have ~u in [0x40800000, 0x40CCCCCC]; >>13 spreads over ~615 buckets.
__device__ __forceinline__ int bucket_of(unsigned long long key) {
    unsigned kh = (unsigned)(key >> 32);
    if (kh < 0x40800000u) return 0;
    unsigned d = (kh - 0x40800000u) >> 13;
    return (d > (NBUCK - 1)) ? (NBUCK - 1) : (int)d;
}

// ---- Kernel 1: LDS-staged argmax (4-way ILP); score + valid-cid per row ----
__global__ __launch_bounds__(ROWS_PB)
void refine_argmax_kernel(const float* __restrict__ probs,
                          float* __restrict__ wscores,        // [B*N]
                          unsigned char* __restrict__ wcid,   // [B*N], 0 if invalid
                          int* __restrict__ survcnt,          // [B] (zeroed here)
                          int* __restrict__ done)             // [B] (zeroed here)
{
    __shared__ __align__(16) float lp[ROWS_PB * NCLS];   // 41472 B
    const int tid = threadIdx.x;
    const size_t base_row = (size_t)blockIdx.x * ROWS_PB;
    const float4* src = (const float4*)(probs + base_row * NCLS);
    float4* dst = (float4*)lp;
    for (int i = tid; i < (ROWS_PB * NCLS) / 4; i += ROWS_PB)   // coalesced stage
        dst[i] = src[i];
    if (blockIdx.x == 0 && tid < BATCH) { survcnt[tid] = 0; done[tid] = 0; }
    __syncthreads();
    const float* prow = lp + tid * NCLS;   // stride 81 dwords (odd) -> conflict-free
    float b0 = prow[0], b1 = prow[1], b2 = prow[2], b3 = prow[3];
    int   c0 = 0,       c1 = 1,       c2 = 2,       c3 = 3;
    for (int c = 4; c + 3 < NCLS; c += 4) {
        float p0 = prow[c],     p1 = prow[c + 1];
        float p2 = prow[c + 2], p3 = prow[c + 3];
        if (p0 > b0) { b0 = p0; c0 = c; }
        if (p1 > b1) { b1 = p1; c1 = c + 1; }
        if (p2 > b2) { b2 = p2; c2 = c + 2; }
        if (p3 > b3) { b3 = p3; c3 = c + 3; }
    }
    { float p = prow[80]; if (p > b0) { b0 = p; c0 = 80; } }
    if (b1 > b0 || (b1 == b0 && c1 < c0)) { b0 = b1; c0 = c1; }  // first-max merge
    if (b3 > b2 || (b3 == b2 && c3 < c2)) { b2 = b3; c2 = c3; }
    if (b2 > b0 || (b2 == b0 && c2 < c0)) { b0 = b2; c0 = c2; }
    size_t row = base_row + tid;
    wscores[row] = b0;
    bool valid = (c0 > 0) && (b0 >= 0.7f);
    wcid[row] = (unsigned char)(valid ? c0 : 0);
}

// ---- Kernel 2: per-(batch,class) NMS; last finished block runs select ----
__global__ __launch_bounds__(128)
void nms_select_kernel(const float* __restrict__ rois,
                       const float* __restrict__ deltas,
                       const float* __restrict__ wscores,
                       const unsigned char* __restrict__ wcid,
                       int* __restrict__ survcnt,              // [B]
                       int* __restrict__ done,                 // [B]
                       unsigned long long* __restrict__ surv64,// [B][SURV_MAX] keys
                       float* __restrict__ out)
{
    const int c = blockIdx.x;            // 0..79 -> cid = c+1
    const int b = blockIdx.y;
    const int cid = c + 1;
    const int tid = threadIdx.x;
    const int lane = tid & 63;
    const int wave = tid >> 6;

    // Byte pool, phases reuse it sequentially:
    //   NMS:    cand u16[128]@0, sortn u16[128]@256, skeys u64[128]@512 (1536 B)
    //   select: keys u64[2048]@0 (16K), hist i32[1024]@16K, candk u64[1024]@20K,
    //           p128 i32[128]@28672
    __shared__ __align__(16) char pool[29312];
    __shared__ int lastFlag, s_cutoff, s_nc, s_over;

    unsigned short* cand  = (unsigned short*)pool;
    unsigned short* sortn = (unsigned short*)(pool + 256);
    unsigned long long* skeys = (unsigned long long*)(pool + 512);

    // ======== NMS for cell (b, cid), wave 0 only (R7-verified logic) ========
    int cnt = 0;
    if (wave == 0) {
        // Preload batch's 2000 wcid bytes: 125 uint4, ONE memory round-trip.
        const uint4* wv = (const uint4*)(wcid + (size_t)b * NBOX);
        uint4 v0 = wv[lane];
        uint4 v1 = make_uint4(0u, 0u, 0u, 0u);
        if (64 + lane < 125) v1 = wv[64 + lane];
        unsigned wds[8] = { v0.x, v0.y, v0.z, v0.w, v1.x, v1.y, v1.z, v1.w };
#pragma unroll
        for (int wq = 0; wq < 8; ++wq) {
#pragma unroll
            for (int k = 0; k < 4; ++k) {
                bool mine = (((wds[wq] >> (8 * k)) & 0xFFu) == (unsigned)cid);
                unsigned long long m = __ballot(mine);
                if (mine) {
                    int pos = cnt + __popcll(m & ((1ULL << lane) - 1ULL));
                    int n = ((wq >> 2) << 10) + lane * 16 + ((wq & 3) << 2) + k;
                    if (pos < 128) cand[pos] = (unsigned short)n;
                }
                cnt += __popcll(m);
            }
        }
        if (cnt > 128) cnt = 128;   // statistically impossible (mean ~25)
        if (cnt > 0) {
            // Keys: total order score desc, n asc (distinct).
            int na = (lane < cnt) ? (int)cand[lane] : -1;
            int nb = (cnt > 64 && 64 + lane < cnt) ? (int)cand[64 + lane] : -1;
            unsigned long long ka = ~0ULL, kb = ~0ULL;
            if (na >= 0) {
                unsigned u = __float_as_uint(wscores[(size_t)b * NBOX + na]) ^ 0x80000000u;
                ka = ((unsigned long long)(~u) << 32) | (unsigned)na;
            }
            if (nb >= 0) {
                unsigned u = __float_as_uint(wscores[(size_t)b * NBOX + nb]) ^ 0x80000000u;
                kb = ((unsigned long long)(~u) << 32) | (unsigned)nb;
            }
            int ra = 0, rb = 0;
            for (int t = 0; t < cnt; ++t) {
                unsigned long long kt = (t < 64) ? shfl_u64(ka, t) : shfl_u64(kb, t - 64);
                ra += (kt < ka) ? 1 : 0;
                if (cnt > 64) rb += (kt < kb) ? 1 : 0;
            }
            if (na >= 0) { sortn[ra] = (unsigned short)na; skeys[ra] = ka; }
            if (nb >= 0) { sortn[rb] = (unsigned short)nb; skeys[rb] = kb; }

            // Refine own sorted slots (OFFSET coords, bit-match reference IoU).
            const float off = (float)cid * 2.0f;
            int sna = (lane < cnt) ? (int)sortn[lane] : -1;
            int snb = (cnt > 64 && 64 + lane < cnt) ? (int)sortn[64 + lane] : -1;
            float ay1 = 0, ax1 = 0, ay2 = 0, ax2 = 0, aar = 0;
            float by1 = 0, bx1 = 0, by2 = 0, bx2 = 0, bar = 0;
            if (sna >= 0) {
                float box[4];
                apply_refine(rois, deltas, (size_t)b * NBOX + sna, cid, box);
                ay1 = __fadd_rn(box[0], off); ax1 = __fadd_rn(box[1], off);
                ay2 = __fadd_rn(box[2], off); ax2 = __fadd_rn(box[3], off);
                aar = __fmul_rn(__fsub_rn(ay2, ay1), __fsub_rn(ax2, ax1));
            }
            if (snb >= 0) {
                float box[4];
                apply_refine(rois, deltas, (size_t)b * NBOX + snb, cid, box);
                by1 = __fadd_rn(box[0], off); bx1 = __fadd_rn(box[1], off);
                by2 = __fadd_rn(box[2], off); bx2 = __fadd_rn(box[3], off);
                bar = __fmul_rn(__fsub_rn(by2, by1), __fsub_rn(bx2, bx1));
            }

            // Greedy NMS via masks + shuffles (zero barriers, zero LDS).
            unsigned long long m0 = (cnt >= 64) ? ~0ULL : ((1ULL << cnt) - 1ULL);
            int rem = cnt - 64;
            unsigned long long m1 =
                (rem <= 0) ? 0ULL : ((rem >= 64) ? ~0ULL : ((1ULL << rem) - 1ULL));
            for (int i = 0; i < cnt - 1; ++i) {
                bool alive_i = (i < 64) ? ((m0 >> i) & 1ULL) : ((m1 >> (i - 64)) & 1ULL);
                if (!alive_i) continue;   // uniform
                float iy1, ix1, iy2, ix2, ia;
                if (i < 64) {
                    iy1 = __shfl(ay1, i); ix1 = __shfl(ax1, i);
                    iy2 = __shfl(ay2, i); ix2 = __shfl(ax2, i); ia = __shfl(aar, i);
                } else {
                    int j = i - 64;
                    iy1 = __shfl(by1, j); ix1 = __shfl(bx1, j);
                    iy2 = __shfl(by2, j); ix2 = __shfl(bx2, j); ia = __shfl(bar, j);
                }
                bool supa = false;
                if (((m0 >> lane) & 1ULL) && lane > i) {
                    float ih = fmaxf(__fsub_rn(fminf(iy2, ay2), fmaxf(iy1, ay1)), 0.f);
                    float iw = fmaxf(__fsub_rn(fminf(ix2, ax2), fmaxf(ix1, ax1)), 0.f);
                    float inter = __fmul_rn(ih, iw);
                    float uni = __fsub_rn(__fadd_rn(ia, aar), inter);
                    supa = (inter / fmaxf(uni, 1e-8f)) > 0.3f;   // IEEE div
                }
                m0 &= ~__ballot(supa);
                if (m1) {
                    bool supb = false;
                    if (((m1 >> lane) & 1ULL) && (64 + lane) > i) {
                        float ih = fmaxf(__fsub_rn(fminf(iy2, by2), fmaxf(iy1, by1)), 0.f);
                        float iw = fmaxf(__fsub_rn(fminf(ix2, bx2), fmaxf(ix1, bx1)), 0.f);
                        float inter = __fmul_rn(ih, iw);
                        float uni = __fsub_rn(__fadd_rn(ia, bar), inter);
                        supb = (inter / fmaxf(uni, 1e-8f)) > 0.3f;
                    }
                    m1 &= ~__ballot(supb);
                }
            }

            // Append survivor KEYS (agent-scope stores: visible to the last block).
            bool keepa = (m0 >> lane) & 1ULL;
            bool keepb = (m1 >> lane) & 1ULL;
            int tot = __popcll(m0) + __popcll(m1);
            int basep = 0;
            if (lane == 0 && tot > 0) basep = atomicAdd(&survcnt[b], tot);
            basep = __shfl(basep, 0);
            if (keepa) {
                int pre = __popcll(m0 & ((1ULL << lane) - 1ULL));
                __hip_atomic_store(&surv64[(size_t)b * SURV_MAX + basep + pre],
                                   skeys[lane], __ATOMIC_RELAXED,
                                   __HIP_MEMORY_SCOPE_AGENT);
            }
            if (keepb) {
                int pre = __popcll(m0) + __popcll(m1 & ((1ULL << lane) - 1ULL));
                __hip_atomic_store(&surv64[(size_t)b * SURV_MAX + basep + pre],
                                   skeys[64 + lane], __ATOMIC_RELAXED,
                                   __HIP_MEMORY_SCOPE_AGENT);
            }
        }
    }

    // ======== done-flag: last finished block of batch b runs select ========
    __threadfence();          // release this block's surv64/survcnt updates
    __syncthreads();          // all lanes fenced before the count
    if (tid == 0) {
        int old = __hip_atomic_fetch_add(&done[b], 1, __ATOMIC_ACQ_REL,
                                         __HIP_MEMORY_SCOPE_AGENT);
        lastFlag = (old == NCLS1 - 1);
    }
    __syncthreads();
    if (!lastFlag) return;
    __threadfence();          // acquire side

    // ======== select: bucket-histogram cutoff + exact rank of ~110 cands ====
    unsigned long long* keys  = (unsigned long long*)pool;            // 16 KB
    int* hist                 = (int*)(pool + 16384);                 // 4 KB
    unsigned long long* candk = (unsigned long long*)(pool + 20480);  // 8 KB
    int* p128                 = (int*)(pool + 28672);                 // 512 B

    int K = __hip_atomic_load(&survcnt[b], __ATOMIC_RELAXED, __HIP_MEMORY_SCOPE_AGENT);
    if (K > SURV_MAX) K = SURV_MAX;

    // Rows [K,100) are all-zero in the reference (d_out is poisoned each launch).
    if (tid < MAXI && tid >= K) {
        float* o = out + ((size_t)b * MAXI + tid) * 6;
        o[0] = 0.f; o[1] = 0.f; o[2] = 0.f; o[3] = 0.f; o[4] = 0.f; o[5] = 0.f;
    }
    if (K == 0) return;

    for (int t = tid; t < NBUCK; t += 128) hist[t] = 0;
    if (tid == 0) { s_nc = 0; s_over = 0; }
    __syncthreads();
    for (int t = tid; t < K; t += 128) {
        unsigned long long k = __hip_atomic_load(&surv64[(size_t)b * SURV_MAX + t],
                                                 __ATOMIC_RELAXED,
                                                 __HIP_MEMORY_SCOPE_AGENT);
        keys[t] = k;
        atomicAdd(&hist[bucket_of(k)], 1);
    }
    __syncthreads();
    int ps = 0;
#pragma unroll
    for (int j = 0; j < 8; ++j) ps += hist[tid * 8 + j];
    p128[tid] = ps;
    __syncthreads();
    if (tid == 0) {
        int target = (K < MAXI) ? K : MAXI;
        int cum = 0, blk = 0;
        while (blk < 128 && cum + p128[blk] < target) { cum += p128[blk]; ++blk; }
        int cb = (blk < 128) ? blk * 8 : NBUCK - 1;
        if (blk < 128) {
            while (cum + hist[cb] < target) { cum += hist[cb]; ++cb; }
        }
        s_cutoff = cb;
    }
    __syncthreads();
    const int cutoff = s_cutoff;
    for (int t = tid; t < K; t += 128) {
        unsigned long long k = keys[t];
        if (bucket_of(k) <= cutoff) {
            int pos = atomicAdd(&s_nc, 1);
            if (pos < CANDCAP) candk[pos] = k; else s_over = 1;
        }
    }
    __syncthreads();
    const int NC = s_nc;

    if (!s_over) {
        // Monotone buckets => candidate-local rank == global rank.
        for (int i = tid; i < NC; i += 128) {
            unsigned long long own = candk[i];
            int rank = 0;
            for (int t = 0; t < NC; ++t) rank += (candk[t] < own) ? 1 : 0;
            if (rank < MAXI) {
                int n = (int)(unsigned)(own & 0xFFFFFFFFull);
                size_t row = (size_t)b * NBOX + n;
                int ocid = wcid[row];   // K1 data: kernel-boundary safe
                float box[4];
                apply_refine(rois, deltas, row, ocid, box);
                float* o = out + ((size_t)b * MAXI + rank) * 6;
                o[0] = box[0]; o[1] = box[1]; o[2] = box[2]; o[3] = box[3];
                o[4] = (float)ocid; o[5] = wscores[row];
            }
        }
    } else {
        // Exact fallback (degenerate score distribution): full O(K^2/128) rank.
        for (int base = 0; base < K; base += 128) {
            int p = base + tid;
            if (p < K) {
                unsigned long long own = keys[p];
                int rank = 0;
                for (int t = 0; t < K; ++t) rank += (keys[t] < own) ? 1 : 0;
                if (rank < MAXI) {
                    int n = (int)(unsigned)(own & 0xFFFFFFFFull);
                    size_t row = (size_t)b * NBOX + n;
                    int ocid = wcid[row];
                    float box[4];
                    apply_refine(rois, deltas, row, ocid, box);
                    float* o = out + ((size_t)b * MAXI + rank) * 6;
                    o[0] = box[0]; o[1] = box[1]; o[2] = box[2]; o[3] = box[3];
                    o[4] = (float)ocid; o[5] = wscores[row];
                }
            }
        }
    }
}

extern "C" void kernel_launch(void* const* d_in, const int* in_sizes, int n_in,
                              void* d_out, int out_size, void* d_ws, size_t ws_size,
                              hipStream_t stream)
{
    const float* rois   = (const float*)d_in[0];  // (B, N, 4)
    const float* probs  = (const float*)d_in[1];  // (B, N, C)
    const float* deltas = (const float*)d_in[2];  // (B, N, C, 4)
    float* out = (float*)d_out;                   // (B, 100, 6)

    // Workspace layout (422 KB), 16B-aligned segments:
    //   [0,64)           survcnt i32 [16]
    //   [64,128)         done    i32 [16]
    //   [128,128128)     wscores f32 [32000]
    //   [128128,160128)  wcid    u8  [32000]
    //   [160128,422272)  surv64  u64 [16][SURV_MAX]
    char* ws = (char*)d_ws;
    int*                survcnt = (int*)(ws);
    int*                done    = (int*)(ws + 64);
    float*              wscores = (float*)(ws + 128);
    unsigned char*      wcid    = (unsigned char*)(ws + 128128);
    unsigned long long* surv64  = (unsigned long long*)(ws + 160128);

    refine_argmax_kernel<<<dim3((BATCH * NBOX) / ROWS_PB), dim3(ROWS_PB), 0, stream>>>(
        probs, wscores, wcid, survcnt, done);
    nms_select_kernel<<<dim3(NCLS1, BATCH), dim3(128), 0, stream>>>(
        rois, deltas, wscores, wcid, survcnt, done, surv64, out);
}

// Round 9
// 127.360 us; speedup vs baseline: 1.3977x; 1.3977x over previous
//
#include <hip/hip_runtime.h>
#include <math.h>

// Problem constants (from reference)
#define BATCH 16
#define NBOX  2000
#define NCLS  81
#define NCLS1 80        // classes 1..80 participate in NMS (class 0 invalid)
#define MAXI  100
#define ROWS_PB 128     // rows per block in phase 1
#define SURV_MAX 2048   // per-batch survivor list capacity (>= NBOX)
#define NBUCK 1024
#define CANDCAP 1024

// Refine with known class id — bit-exact vs numpy reference (absmax 0.0 R1-R8).
__device__ __forceinline__ void apply_refine(
    const float* __restrict__ rois, const float* __restrict__ deltas,
    size_t row, int cid, float box[4])
{
    const float4 dr = *(const float4*)(deltas + (row * NCLS + cid) * 4);
    const float4 r  = *(const float4*)(rois + row * 4);
    float dy = __fmul_rn(dr.x, 0.1f);
    float dx = __fmul_rn(dr.y, 0.1f);
    float dh = __fmul_rn(dr.z, 0.2f);
    float dw = __fmul_rn(dr.w, 0.2f);
    float h = __fsub_rn(r.z, r.x);
    float w = __fsub_rn(r.w, r.y);
    float cy = __fadd_rn(r.x, __fmul_rn(0.5f, h));
    float cx = __fadd_rn(r.y, __fmul_rn(0.5f, w));
    cy = __fadd_rn(cy, __fmul_rn(dy, h));
    cx = __fadd_rn(cx, __fmul_rn(dx, w));
    h = __fmul_rn(h, (float)exp((double)dh));   // correctly-rounded f32 exp
    w = __fmul_rn(w, (float)exp((double)dw));
    float hy = __fmul_rn(0.5f, h), hx = __fmul_rn(0.5f, w);
    box[0] = fminf(fmaxf(__fsub_rn(cy, hy), 0.f), 1.f);
    box[1] = fminf(fmaxf(__fsub_rn(cx, hx), 0.f), 1.f);
    box[2] = fminf(fmaxf(__fadd_rn(cy, hy), 0.f), 1.f);
    box[3] = fminf(fmaxf(__fadd_rn(cx, hx), 0.f), 1.f);
}

__device__ __forceinline__ unsigned long long shfl_u64(unsigned long long v, int src) {
    unsigned lo = __shfl((unsigned)v, src);
    unsigned hi = __shfl((unsigned)(v >> 32), src);
    return ((unsigned long long)hi << 32) | lo;
}

// Monotonic score-bucket (verified bit-exact in R8): keys ascend == scores
// descend; valid scores in [0.7,1) have ~u in [0x40800000, 0x40CCCCCC];
// >>13 spreads over ~615 buckets. k' < k  =>  bucket(k') <= bucket(k).
__device__ __forceinline__ int bucket_of(unsigned long long key) {
    unsigned kh = (unsigned)(key >> 32);
    if (kh < 0x40800000u) return 0;
    unsigned d = (kh - 0x40800000u) >> 13;
    return (d > (NBUCK - 1)) ? (NBUCK - 1) : (int)d;
}

// ---- Kernel 1: LDS-staged argmax (4-way ILP); score + valid-cid per row ----
__global__ __launch_bounds__(ROWS_PB)
void refine_argmax_kernel(const float* __restrict__ probs,
                          float* __restrict__ wscores,        // [B*N]
                          unsigned char* __restrict__ wcid,   // [B*N], 0 if invalid
                          int* __restrict__ survcnt)          // [B] (zeroed here)
{
    __shared__ __align__(16) float lp[ROWS_PB * NCLS];   // 41472 B
    const int tid = threadIdx.x;
    const size_t base_row = (size_t)blockIdx.x * ROWS_PB;
    const float4* src = (const float4*)(probs + base_row * NCLS);
    float4* dst = (float4*)lp;
    for (int i = tid; i < (ROWS_PB * NCLS) / 4; i += ROWS_PB)   // coalesced stage
        dst[i] = src[i];
    if (blockIdx.x == 0 && tid < BATCH) survcnt[tid] = 0;   // ordered by kernel boundary
    __syncthreads();
    const float* prow = lp + tid * NCLS;   // stride 81 dwords (odd) -> conflict-free
    float b0 = prow[0], b1 = prow[1], b2 = prow[2], b3 = prow[3];
    int   c0 = 0,       c1 = 1,       c2 = 2,       c3 = 3;
    for (int c = 4; c + 3 < NCLS; c += 4) {
        float p0 = prow[c],     p1 = prow[c + 1];
        float p2 = prow[c + 2], p3 = prow[c + 3];
        if (p0 > b0) { b0 = p0; c0 = c; }
        if (p1 > b1) { b1 = p1; c1 = c + 1; }
        if (p2 > b2) { b2 = p2; c2 = c + 2; }
        if (p3 > b3) { b3 = p3; c3 = c + 3; }
    }
    { float p = prow[80]; if (p > b0) { b0 = p; c0 = 80; } }
    if (b1 > b0 || (b1 == b0 && c1 < c0)) { b0 = b1; c0 = c1; }  // first-max merge
    if (b3 > b2 || (b3 == b2 && c3 < c2)) { b2 = b3; c2 = c3; }
    if (b2 > b0 || (b2 == b0 && c2 < c0)) { b0 = b2; c0 = c2; }
    size_t row = base_row + tid;
    wscores[row] = b0;
    bool valid = (c0 > 0) && (b0 >= 0.7f);
    wcid[row] = (unsigned char)(valid ? c0 : 0);
}

// ---- Kernel 2: per-(batch,class) scan + shuffle rank-sort + shuffle NMS ----
// Appends survivor KEYS (u64) to the per-batch list; plain stores, plain atomic.
__global__ __launch_bounds__(64)
void classnms_kernel(const float* __restrict__ rois,
                     const float* __restrict__ deltas,
                     const float* __restrict__ wscores,
                     const unsigned char* __restrict__ wcid,
                     int* __restrict__ survcnt,                  // [B]
                     unsigned long long* __restrict__ surv64)    // [B][SURV_MAX] keys
{
    const int c = blockIdx.x;            // 0..79 -> cid = c+1
    const int b = blockIdx.y;
    const int cid = c + 1;
    const int lane = threadIdx.x;
    __shared__ unsigned short cand[128];
    __shared__ unsigned short sortn[128];
    __shared__ unsigned long long skeys[128];

    // Preload batch's 2000 wcid bytes: exactly 125 uint4; ONE memory round-trip.
    const uint4* wv = (const uint4*)(wcid + (size_t)b * NBOX);
    uint4 v0 = wv[lane];
    uint4 v1 = make_uint4(0u, 0u, 0u, 0u);                       // byte 0 != cid (cid>=1)
    if (64 + lane < 125) v1 = wv[64 + lane];

    // 32 ballot rounds over register bytes. cand[] order is scrambled (k-major)
    // but the rank-sort below makes final order independent of cand order.
    int cnt = 0;
    unsigned wds[8] = { v0.x, v0.y, v0.z, v0.w, v1.x, v1.y, v1.z, v1.w };
#pragma unroll
    for (int wq = 0; wq < 8; ++wq) {
#pragma unroll
        for (int k = 0; k < 4; ++k) {
            bool mine = (((wds[wq] >> (8 * k)) & 0xFFu) == (unsigned)cid);
            unsigned long long m = __ballot(mine);
            if (mine) {
                int pos = cnt + __popcll(m & ((1ULL << lane) - 1ULL));
                int n = ((wq >> 2) << 10) + lane * 16 + ((wq & 3) << 2) + k;
                if (pos < 128) cand[pos] = (unsigned short)n;
            }
            cnt += __popcll(m);
        }
    }
    if (cnt == 0) return;
    if (cnt > 128) cnt = 128;   // statistically impossible (mean ~25)

    // Per-lane keys; total order: score desc, n asc (keys distinct).
    int na = (lane < cnt) ? (int)cand[lane] : -1;
    int nb = (cnt > 64 && 64 + lane < cnt) ? (int)cand[64 + lane] : -1;
    unsigned long long ka = ~0ULL, kb = ~0ULL;
    if (na >= 0) {
        unsigned u = __float_as_uint(wscores[(size_t)b * NBOX + na]) ^ 0x80000000u;
        ka = ((unsigned long long)(~u) << 32) | (unsigned)na;
    }
    if (nb >= 0) {
        unsigned u = __float_as_uint(wscores[(size_t)b * NBOX + nb]) ^ 0x80000000u;
        kb = ((unsigned long long)(~u) << 32) | (unsigned)nb;
    }
    int ra = 0, rb = 0;
    for (int t = 0; t < cnt; ++t) {
        unsigned long long kt = (t < 64) ? shfl_u64(ka, t) : shfl_u64(kb, t - 64);
        ra += (kt < ka) ? 1 : 0;
        if (cnt > 64) rb += (kt < kb) ? 1 : 0;
    }
    if (na >= 0) { sortn[ra] = (unsigned short)na; skeys[ra] = ka; }
    if (nb >= 0) { sortn[rb] = (unsigned short)nb; skeys[rb] = kb; }
    __syncthreads();

    // Refine own sorted slots (OFFSET coords, bit-match reference IoU).
    const float off = (float)cid * 2.0f;
    int sna = (lane < cnt) ? (int)sortn[lane] : -1;
    int snb = (cnt > 64 && 64 + lane < cnt) ? (int)sortn[64 + lane] : -1;
    float ay1 = 0, ax1 = 0, ay2 = 0, ax2 = 0, aar = 0;
    float by1 = 0, bx1 = 0, by2 = 0, bx2 = 0, bar = 0;
    if (sna >= 0) {
        float box[4];
        apply_refine(rois, deltas, (size_t)b * NBOX + sna, cid, box);
        ay1 = __fadd_rn(box[0], off); ax1 = __fadd_rn(box[1], off);
        ay2 = __fadd_rn(box[2], off); ax2 = __fadd_rn(box[3], off);
        aar = __fmul_rn(__fsub_rn(ay2, ay1), __fsub_rn(ax2, ax1));
    }
    if (snb >= 0) {
        float box[4];
        apply_refine(rois, deltas, (size_t)b * NBOX + snb, cid, box);
        by1 = __fadd_rn(box[0], off); bx1 = __fadd_rn(box[1], off);
        by2 = __fadd_rn(box[2], off); bx2 = __fadd_rn(box[3], off);
        bar = __fmul_rn(__fsub_rn(by2, by1), __fsub_rn(bx2, bx1));
    }

    // Greedy NMS via masks + shuffles (zero barriers, zero LDS).
    unsigned long long m0 = (cnt >= 64) ? ~0ULL : ((1ULL << cnt) - 1ULL);
    int rem = cnt - 64;
    unsigned long long m1 = (rem <= 0) ? 0ULL : ((rem >= 64) ? ~0ULL : ((1ULL << rem) - 1ULL));
    for (int i = 0; i < cnt - 1; ++i) {
        bool alive_i = (i < 64) ? ((m0 >> i) & 1ULL) : ((m1 >> (i - 64)) & 1ULL);
        if (!alive_i) continue;   // uniform
        float iy1, ix1, iy2, ix2, ia;
        if (i < 64) {
            iy1 = __shfl(ay1, i); ix1 = __shfl(ax1, i);
            iy2 = __shfl(ay2, i); ix2 = __shfl(ax2, i); ia = __shfl(aar, i);
        } else {
            int j = i - 64;
            iy1 = __shfl(by1, j); ix1 = __shfl(bx1, j);
            iy2 = __shfl(by2, j); ix2 = __shfl(bx2, j); ia = __shfl(bar, j);
        }
        bool supa = false;
        if (((m0 >> lane) & 1ULL) && lane > i) {
            float ih = fmaxf(__fsub_rn(fminf(iy2, ay2), fmaxf(iy1, ay1)), 0.f);
            float iw = fmaxf(__fsub_rn(fminf(ix2, ax2), fmaxf(ix1, ax1)), 0.f);
            float inter = __fmul_rn(ih, iw);
            float uni = __fsub_rn(__fadd_rn(ia, aar), inter);
            supa = (inter / fmaxf(uni, 1e-8f)) > 0.3f;   // IEEE div, matches ref
        }
        m0 &= ~__ballot(supa);
        if (m1) {
            bool supb = false;
            if (((m1 >> lane) & 1ULL) && (64 + lane) > i) {
                float ih = fmaxf(__fsub_rn(fminf(iy2, by2), fmaxf(iy1, by1)), 0.f);
                float iw = fmaxf(__fsub_rn(fminf(ix2, bx2), fmaxf(ix1, bx1)), 0.f);
                float inter = __fmul_rn(ih, iw);
                float uni = __fsub_rn(__fadd_rn(ia, bar), inter);
                supb = (inter / fmaxf(uni, 1e-8f)) > 0.3f;
            }
            m1 &= ~__ballot(supb);
        }
    }

    // Append survivor keys: one atomic per block; plain stores (kernel boundary
    // publishes them to K3 — no fences needed).
    bool keepa = (m0 >> lane) & 1ULL;
    bool keepb = (m1 >> lane) & 1ULL;
    int tot = __popcll(m0) + __popcll(m1);
    int basep = 0;
    if (lane == 0 && tot > 0) basep = atomicAdd(&survcnt[b], tot);
    basep = __shfl(basep, 0);
    if (keepa) {
        int pre = __popcll(m0 & ((1ULL << lane) - 1ULL));
        surv64[(size_t)b * SURV_MAX + basep + pre] = skeys[lane];
    }
    if (keepb) {
        int pre = __popcll(m0) + __popcll(m1 & ((1ULL << lane) - 1ULL));
        surv64[(size_t)b * SURV_MAX + basep + pre] = skeys[64 + lane];
    }
}

// ---- Kernel 3: bucket-histogram top-100 select (R8-verified algorithm) ----
// Grid (B) x 256: one block per batch; NC ~ 150-300 exact-rank candidates.
__global__ __launch_bounds__(256)
void select_kernel(const float* __restrict__ rois,
                   const float* __restrict__ deltas,
                   const float* __restrict__ wscores,
                   const unsigned char* __restrict__ wcid,
                   const int* __restrict__ survcnt,
                   const unsigned long long* __restrict__ surv64,
                   float* __restrict__ out)
{
    const int b = blockIdx.x;
    const int tid = threadIdx.x;
    __shared__ __align__(16) unsigned long long keys[SURV_MAX];   // 16 KB
    __shared__ int hist[NBUCK];                                    // 4 KB
    __shared__ unsigned long long candk[CANDCAP];                  // 8 KB
    __shared__ int p256[256];                                      // 1 KB
    __shared__ int s_cutoff, s_nc, s_over;

    int K = survcnt[b]; if (K > SURV_MAX) K = SURV_MAX;

    // Rows [K,100) are all-zero in the reference (d_out is poisoned each launch).
    if (tid < MAXI && tid >= K) {
        float* o = out + ((size_t)b * MAXI + tid) * 6;
        o[0] = 0.f; o[1] = 0.f; o[2] = 0.f; o[3] = 0.f; o[4] = 0.f; o[5] = 0.f;
    }
    if (K == 0) return;

    for (int t = tid; t < NBUCK; t += 256) hist[t] = 0;
    if (tid == 0) { s_nc = 0; s_over = 0; }
    __syncthreads();
    for (int t = tid; t < K; t += 256) {
        unsigned long long k = surv64[(size_t)b * SURV_MAX + t];   // coalesced
        keys[t] = k;
        atomicAdd(&hist[bucket_of(k)], 1);
    }
    __syncthreads();
    int ps = 0;
#pragma unroll
    for (int j = 0; j < 4; ++j) ps += hist[tid * 4 + j];
    p256[tid] = ps;
    __syncthreads();
    if (tid == 0) {
        int target = (K < MAXI) ? K : MAXI;
        int cum = 0, blk = 0;
        while (blk < 256 && cum + p256[blk] < target) { cum += p256[blk]; ++blk; }
        int cb = (blk < 256) ? blk * 4 : NBUCK - 1;
        if (blk < 256) {
            while (cum + hist[cb] < target) { cum += hist[cb]; ++cb; }
        }
        s_cutoff = cb;
    }
    __syncthreads();
    const int cutoff = s_cutoff;
    for (int t = tid; t < K; t += 256) {
        unsigned long long k = keys[t];
        if (bucket_of(k) <= cutoff) {
            int pos = atomicAdd(&s_nc, 1);
            if (pos < CANDCAP) candk[pos] = k; else s_over = 1;
        }
    }
    __syncthreads();
    const int NC = s_nc;

    if (!s_over) {
        // Monotone buckets => candidate-local rank == global rank; every
        // global-top-100 key lands in a bucket <= cutoff.
        for (int i = tid; i < NC; i += 256) {
            unsigned long long own = candk[i];
            int rank = 0;
            for (int t = 0; t < NC; ++t) rank += (candk[t] < own) ? 1 : 0;
            if (rank < MAXI) {
                int n = (int)(unsigned)(own & 0xFFFFFFFFull);
                size_t row = (size_t)b * NBOX + n;
                int ocid = wcid[row];   // survivors always have cid>0
                float box[4];
                apply_refine(rois, deltas, row, ocid, box);
                float* o = out + ((size_t)b * MAXI + rank) * 6;
                o[0] = box[0]; o[1] = box[1]; o[2] = box[2]; o[3] = box[3];
                o[4] = (float)ocid; o[5] = wscores[row];
            }
        }
    } else {
        // Exact fallback (degenerate score distribution): full rank over K.
        for (int base = 0; base < K; base += 256) {
            int p = base + tid;
            if (p < K) {
                unsigned long long own = keys[p];
                int rank = 0;
                for (int t = 0; t < K; ++t) rank += (keys[t] < own) ? 1 : 0;
                if (rank < MAXI) {
                    int n = (int)(unsigned)(own & 0xFFFFFFFFull);
                    size_t row = (size_t)b * NBOX + n;
                    int ocid = wcid[row];
                    float box[4];
                    apply_refine(rois, deltas, row, ocid, box);
                    float* o = out + ((size_t)b * MAXI + rank) * 6;
                    o[0] = box[0]; o[1] = box[1]; o[2] = box[2]; o[3] = box[3];
                    o[4] = (float)ocid; o[5] = wscores[row];
                }
            }
        }
    }
}

extern "C" void kernel_launch(void* const* d_in, const int* in_sizes, int n_in,
                              void* d_out, int out_size, void* d_ws, size_t ws_size,
                              hipStream_t stream)
{
    const float* rois   = (const float*)d_in[0];  // (B, N, 4)
    const float* probs  = (const float*)d_in[1];  // (B, N, C)
    const float* deltas = (const float*)d_in[2];  // (B, N, C, 4)
    float* out = (float*)d_out;                   // (B, 100, 6)

    // Workspace layout (422 KB), 16B-aligned segments:
    //   [0,64)           survcnt i32 [16]
    //   [64,128064)      wscores f32 [32000]
    //   [128064,160064)  wcid    u8  [32000]
    //   [160064,422208)  surv64  u64 [16][SURV_MAX]
    char* ws = (char*)d_ws;
    int*                survcnt = (int*)(ws);
    float*              wscores = (float*)(ws + 64);
    unsigned char*      wcid    = (unsigned char*)(ws + 128064);
    unsigned long long* surv64  = (unsigned long long*)(ws + 160064);

    refine_argmax_kernel<<<dim3((BATCH * NBOX) / ROWS_PB), dim3(ROWS_PB), 0, stream>>>(
        probs, wscores, wcid, survcnt);
    classnms_kernel<<<dim3(NCLS1, BATCH), dim3(64), 0, stream>>>(
        rois, deltas, wscores, wcid, survcnt, surv64);
    select_kernel<<<dim3(BATCH), dim3(256), 0, stream>>>(
        rois, deltas, wscores, wcid, survcnt, surv64, out);
}